// Round 4
// baseline (512.843 us; speedup 1.0000x reference)
//
#include <hip/hip_runtime.h>

#define DIM 4096
using F2 = float2;

// 256 threads/block, one block per batch element. 16 float2 amps per thread.
// Amplitude index a (12 bits): per-layout, 4 bits are "reg bits" (the r index,
// r bit3 -> highest of the quad's bit positions) and 8 bits are thread bits
// (t bit7 -> highest remaining position). Qubit q lives at bit (11-q).
// Layout A/H: quad {0,1,2,3}  -> bits {11,10,9,8}
// Layout B/G: quad {3,4,5,6}  -> bits {8,7,6,5}
// Layout C/F: quad {6,7,8,9}  -> bits {5,4,3,2}
// Layout DE : quad {9,10,11,0}-> bits {2,1,0,11}

__device__ __forceinline__ int swz(int i)            { return i ^ (i >> 6); }  // LDS anti-conflict
__device__ __forceinline__ int addrA(int r, int t)   { return (r << 8) | t; }
__device__ __forceinline__ int addrB(int r, int t)   { return ((t >> 5) << 9) | (r << 5) | (t & 31); }
__device__ __forceinline__ int addrC(int r, int t)   { return ((t >> 2) << 6) | (r << 2) | (t & 3); }
__device__ __forceinline__ int addrD(int r, int t)   { return ((r >> 3) << 11) | (t << 3) | (r & 7); }

__device__ __forceinline__ void build_u(float tx, float ty, float tz, float* u) {
    float sx = sinf(0.5f*tx), cx = cosf(0.5f*tx);
    float sy = sinf(0.5f*ty), cy = cosf(0.5f*ty);
    float sz = sinf(0.5f*tz), cz = cosf(0.5f*tz);
    float A00r = cy*cx, A00i =  sy*sx;     // A = Ry*Rx
    float A01r = -sy*cx, A01i = -cy*sx;
    float A10r =  sy*cx, A10i = -cy*sx;
    float A11r =  cy*cx, A11i = -sy*sx;
    // U = Rz*A: row0 *= (cz - i sz), row1 *= (cz + i sz)   [math verified rounds 1 & 3]
    u[0] = cz*A00r + sz*A00i;  u[1] = cz*A00i - sz*A00r;
    u[2] = cz*A01r + sz*A01i;  u[3] = cz*A01i - sz*A01r;
    u[4] = cz*A10r - sz*A10i;  u[5] = cz*A10i + sz*A10r;
    u[6] = cz*A11r - sz*A11i;  u[7] = cz*A11i + sz*A11r;
}

template<int M>  // fused 1q gate on reg-bit M pairs (compile-time)
__device__ __forceinline__ void g1q(F2* amp, const float* u) {
    float u0=u[0],u1=u[1],u2=u[2],u3=u[3],u4=u[4],u5=u[5],u6=u[6],u7=u[7];
#pragma unroll
    for (int r0 = 0; r0 < 16; ++r0) {
        if (r0 & M) continue;
        const int r1 = r0 + M;
        F2 a0 = amp[r0], a1 = amp[r1];
        amp[r0].x = u0*a0.x - u1*a0.y + u2*a1.x - u3*a1.y;
        amp[r0].y = u0*a0.y + u1*a0.x + u2*a1.y + u3*a1.x;
        amp[r1].x = u4*a0.x - u5*a0.y + u6*a1.x - u7*a1.y;
        amp[r1].y = u4*a0.y + u5*a0.x + u6*a1.y + u7*a1.x;
    }
}

template<int MC, int MT>  // CRX: control reg bit MC (=1), RX on target reg bit MT
__device__ __forceinline__ void crx(F2* amp, float cc, float ss) {
#pragma unroll
    for (int r0 = 0; r0 < 16; ++r0) {
        if (!(r0 & MC) || (r0 & MT)) continue;
        const int r1 = r0 + MT;
        F2 a0 = amp[r0], a1 = amp[r1];
        amp[r0] = make_float2(cc*a0.x + ss*a1.y, cc*a0.y - ss*a1.x);
        amp[r1] = make_float2(ss*a0.y + cc*a1.x, -ss*a0.x + cc*a1.y);
    }
}

template<int M>  // fold <X_q>,<Y_q>,<Z_q> partials into acc via W (reduced later)
__device__ __forceinline__ void expv(const F2* amp, const float* __restrict__ W,
                                     int q, float* acc) {
    float xr = 0.f, xi = 0.f, zz = 0.f;
#pragma unroll
    for (int r0 = 0; r0 < 16; ++r0) {
        if (r0 & M) continue;
        const int r1 = r0 + M;
        F2 a0 = amp[r0], a1 = amp[r1];
        zz += a0.x*a0.x + a0.y*a0.y - a1.x*a1.x - a1.y*a1.y;
        xr += a0.x*a1.x + a0.y*a1.y;   // Re(conj(a0)*a1)
        xi += a0.x*a1.y - a0.y*a1.x;   // Im(conj(a0)*a1)
    }
    xr *= 2.f; xi *= 2.f;              // X=2ReS, Y=2ImS; pairs disjoint across threads
#pragma unroll
    for (int c = 0; c < 10; ++c)
        acc[c] += W[c*36 + q]*xr + W[c*36 + 12 + q]*xi + W[c*36 + 24 + q]*zz;
}

#define XPOSE(CUR, NXT) \
  { _Pragma("unroll") for (int r = 0; r < 16; ++r) psi[swz(CUR(r, t))] = amp[r]; \
    __syncthreads(); \
    _Pragma("unroll") for (int r = 0; r < 16; ++r) amp[r] = psi[swz(NXT(r, t))]; \
    __syncthreads(); }

#define U0(q, M)        g1q<M>(amp, uT[q])
#define U1(q, M)        g1q<M>(amp, uT[12 + (q)])
#define CR0(c, MC, MT)  crx<MC, MT>(amp, csT[c][0], csT[c][1])
#define CR1(c, MC, MT)  crx<MC, MT>(amp, csT[23 - (c)][0], csT[23 - (c)][1])
#define EXPV(q, M)      expv<M>(amp, W, q, acc)

__global__ __launch_bounds__(256, 4)
void qsim_kernel(const float* __restrict__ sv,      // [B, 4096]
                 const float* __restrict__ ang,     // [96]
                 const float* __restrict__ W,       // [10, 36]
                 const float* __restrict__ bvec,    // [10]
                 float* __restrict__ out)           // [B, 10]
{
    __shared__ F2    psi[DIM];       // 32 KB transpose buffer
    __shared__ float uT[24][8];      // fused Rz*Ry*Rx per (layer,qubit)
    __shared__ float csT[24][2];     // CRX (cos,sin); csT[12+g] is layer-1 tape slot g (ctrl=11-g)
    __shared__ float red[4][10];

    const int t = threadIdx.x;
    const int b = blockIdx.x;

    if (t < 24) {
        int l = t / 12, q = t % 12;
        build_u(ang[48*l + q], ang[48*l + 12 + q], ang[48*l + 24 + q], uT[t]);
    } else if (t >= 32 && t < 56) {
        int g = t - 32;
        float th = 0.5f * ang[g < 12 ? 36 + g : 72 + g];   // 84 + (g-12)
        csT[g][0] = cosf(th);
        csT[g][1] = sinf(th);
    }

    F2 amp[16];
    const float* svb = sv + (size_t)b * DIM;
#pragma unroll
    for (int r = 0; r < 16; ++r)                    // layout A, coalesced
        amp[r] = make_float2(svb[(r << 8) | t], 0.f);
    __syncthreads();                                // publish uT/csT

    float acc[10];
#pragma unroll
    for (int c = 0; c < 10; ++c) acc[c] = 0.f;

    // ---- A {0,1,2,3}: L0 1q on 0..3; L0 ring (0,1),(1,2),(2,3) ----
    U0(0, 8); U0(1, 4); U0(2, 2); U0(3, 1);
    CR0(0, 8, 4); CR0(1, 4, 2); CR0(2, 2, 1);
    XPOSE(addrA, addrB);

    // ---- B {3,4,5,6}: L0 1q on 4,5,6; L0 ring (3,4),(4,5),(5,6) ----
    U0(4, 4); U0(5, 2); U0(6, 1);
    CR0(3, 8, 4); CR0(4, 4, 2); CR0(5, 2, 1);
    XPOSE(addrB, addrC);

    // ---- C {6,7,8,9}: L0 1q on 7,8,9; L0 ring (6,7),(7,8),(8,9) ----
    U0(7, 4); U0(8, 2); U0(9, 1);
    CR0(6, 8, 4); CR0(7, 4, 2); CR0(8, 2, 1);
    XPOSE(addrC, addrD);

    // ---- DE {9,10,11,0} (q0->8, q9->4, q10->2, q11->1):
    //      L0 1q on 10,11; L0 ring (9,10),(10,11),(11,0);
    //      L1 1q on 9,10,11,0; L1 ring (11,0),(10,11),(9,10); expv 10,11 ----
    U0(10, 2); U0(11, 1);
    CR0(9, 4, 2); CR0(10, 2, 1); CR0(11, 1, 8);
    U1(9, 4); U1(10, 2); U1(11, 1); U1(0, 8);
    CR1(11, 1, 8); CR1(10, 2, 1); CR1(9, 4, 2);
    EXPV(10, 2); EXPV(11, 1);
    XPOSE(addrD, addrC);

    // ---- F {6,7,8,9}: L1 1q on 6,7,8; L1 ring (8,9),(7,8),(6,7); expv 7,8,9 ----
    U1(6, 8); U1(7, 4); U1(8, 2);
    CR1(8, 2, 1); CR1(7, 4, 2); CR1(6, 8, 4);
    EXPV(9, 1); EXPV(8, 2); EXPV(7, 4);
    XPOSE(addrC, addrB);

    // ---- G {3,4,5,6}: L1 1q on 3,4,5; L1 ring (5,6),(4,5),(3,4); expv 4,5,6 ----
    U1(3, 8); U1(4, 4); U1(5, 2);
    CR1(5, 2, 1); CR1(4, 4, 2); CR1(3, 8, 4);
    EXPV(6, 1); EXPV(5, 2); EXPV(4, 4);
    XPOSE(addrB, addrA);

    // ---- H {0,1,2,3}: L1 1q on 1,2; L1 ring (2,3),(1,2),(0,1); expv 0..3 ----
    U1(1, 4); U1(2, 2);
    CR1(2, 2, 1); CR1(1, 4, 2); CR1(0, 8, 4);
    EXPV(0, 8); EXPV(1, 4); EXPV(2, 2); EXPV(3, 1);

    // ---- reduce acc over wave, then over the 4 waves, add bias, store ----
#pragma unroll
    for (int c = 0; c < 10; ++c)
#pragma unroll
        for (int off = 32; off; off >>= 1) acc[c] += __shfl_xor(acc[c], off);
    const int lane = t & 63, w = t >> 6;
    if (lane == 0)
#pragma unroll
        for (int c = 0; c < 10; ++c) red[w][c] = acc[c];
    __syncthreads();
    if (t < 10)
        out[(size_t)b * 10 + t] = red[0][t] + red[1][t] + red[2][t] + red[3][t] + bvec[t];
}

extern "C" void kernel_launch(void* const* d_in, const int* in_sizes, int n_in,
                              void* d_out, int out_size, void* d_ws, size_t ws_size,
                              hipStream_t stream) {
    const float* sv     = (const float*)d_in[0];
    const float* angles = (const float*)d_in[1];
    const float* W      = (const float*)d_in[2];
    const float* bvec   = (const float*)d_in[3];
    float* out = (float*)d_out;
    int batch = in_sizes[0] / DIM;   // 2048
    qsim_kernel<<<batch, 256, 0, stream>>>(sv, angles, W, bvec, out);
}

// Round 5
// 259.805 us; speedup vs baseline: 1.9740x; 1.9740x over previous
//
#include <hip/hip_runtime.h>

#define DIM 4096
using F2 = float2;

// 256 threads/block, one block per batch element. 16 float2 amps per thread.
// Amplitude index a (12 bits): per-layout, 4 bits are "reg bits" (the r index,
// r bit3 -> highest of the quad's bit positions) and 8 bits are thread bits
// (t bit7 -> highest remaining position). Qubit q lives at bit (11-q).
// Layout A/H: quad {0,1,2,3}  -> bits {11,10,9,8}
// Layout B/G: quad {3,4,5,6}  -> bits {8,7,6,5}
// Layout C/F: quad {6,7,8,9}  -> bits {5,4,3,2}
// Layout DE : quad {9,10,11,0}-> bits {2,1,0,11}

__device__ __forceinline__ int swz(int i)            { return i ^ (i >> 6); }  // LDS anti-conflict
__device__ __forceinline__ int addrA(int r, int t)   { return (r << 8) | t; }
__device__ __forceinline__ int addrB(int r, int t)   { return ((t >> 5) << 9) | (r << 5) | (t & 31); }
__device__ __forceinline__ int addrC(int r, int t)   { return ((t >> 2) << 6) | (r << 2) | (t & 3); }
__device__ __forceinline__ int addrD(int r, int t)   { return ((r >> 3) << 11) | (t << 3) | (r & 7); }

__device__ __forceinline__ void build_u(float tx, float ty, float tz, float* u) {
    float sx = sinf(0.5f*tx), cx = cosf(0.5f*tx);
    float sy = sinf(0.5f*ty), cy = cosf(0.5f*ty);
    float sz = sinf(0.5f*tz), cz = cosf(0.5f*tz);
    float A00r = cy*cx, A00i =  sy*sx;     // A = Ry*Rx
    float A01r = -sy*cx, A01i = -cy*sx;
    float A10r =  sy*cx, A10i = -cy*sx;
    float A11r =  cy*cx, A11i = -sy*sx;
    // U = Rz*A: row0 *= (cz - i sz), row1 *= (cz + i sz)   [math verified rounds 1/3/4]
    u[0] = cz*A00r + sz*A00i;  u[1] = cz*A00i - sz*A00r;
    u[2] = cz*A01r + sz*A01i;  u[3] = cz*A01i - sz*A01r;
    u[4] = cz*A10r - sz*A10i;  u[5] = cz*A10i + sz*A10r;
    u[6] = cz*A11r - sz*A11i;  u[7] = cz*A11i + sz*A11r;
}

template<int M>  // fused 1q gate on reg-bit M pairs (compile-time)
__device__ __forceinline__ void g1q(F2* amp, const float* u) {
    float u0=u[0],u1=u[1],u2=u[2],u3=u[3],u4=u[4],u5=u[5],u6=u[6],u7=u[7];
#pragma unroll
    for (int r0 = 0; r0 < 16; ++r0) {
        if (r0 & M) continue;
        const int r1 = r0 + M;
        F2 a0 = amp[r0], a1 = amp[r1];
        amp[r0].x = u0*a0.x - u1*a0.y + u2*a1.x - u3*a1.y;
        amp[r0].y = u0*a0.y + u1*a0.x + u2*a1.y + u3*a1.x;
        amp[r1].x = u4*a0.x - u5*a0.y + u6*a1.x - u7*a1.y;
        amp[r1].y = u4*a0.y + u5*a0.x + u6*a1.y + u7*a1.x;
    }
}

template<int MC, int MT>  // CRX: control reg bit MC (=1), RX on target reg bit MT
__device__ __forceinline__ void crx(F2* amp, float cc, float ss) {
#pragma unroll
    for (int r0 = 0; r0 < 16; ++r0) {
        if (!(r0 & MC) || (r0 & MT)) continue;
        const int r1 = r0 + MT;
        F2 a0 = amp[r0], a1 = amp[r1];
        amp[r0] = make_float2(cc*a0.x + ss*a1.y, cc*a0.y - ss*a1.x);
        amp[r1] = make_float2(ss*a0.y + cc*a1.x, -ss*a0.x + cc*a1.y);
    }
}

template<int M>  // fold <X_q>,<Y_q>,<Z_q> partials into acc via W (reduced later)
__device__ __forceinline__ void expv(const F2* amp, const float* __restrict__ W,
                                     int q, float* acc) {
    float xr = 0.f, xi = 0.f, zz = 0.f;
#pragma unroll
    for (int r0 = 0; r0 < 16; ++r0) {
        if (r0 & M) continue;
        const int r1 = r0 + M;
        F2 a0 = amp[r0], a1 = amp[r1];
        zz += a0.x*a0.x + a0.y*a0.y - a1.x*a1.x - a1.y*a1.y;
        xr += a0.x*a1.x + a0.y*a1.y;   // Re(conj(a0)*a1)
        xi += a0.x*a1.y - a0.y*a1.x;   // Im(conj(a0)*a1)
    }
    xr *= 2.f; xi *= 2.f;              // X=2ReS, Y=2ImS; pairs disjoint across threads
#pragma unroll
    for (int c = 0; c < 10; ++c)
        acc[c] += W[c*36 + q]*xr + W[c*36 + 12 + q]*xi + W[c*36 + 24 + q]*zz;
}

#define XPOSE(CUR, NXT) \
  { _Pragma("unroll") for (int r = 0; r < 16; ++r) psi[swz(CUR(r, t))] = amp[r]; \
    __syncthreads(); \
    _Pragma("unroll") for (int r = 0; r < 16; ++r) amp[r] = psi[swz(NXT(r, t))]; \
    __syncthreads(); }

#define U0(q, M)        g1q<M>(amp, uT[q])
#define U1(q, M)        g1q<M>(amp, uT[12 + (q)])
#define CR0(c, MC, MT)  crx<MC, MT>(amp, csT[c][0], csT[c][1])
#define CR1(c, MC, MT)  crx<MC, MT>(amp, csT[23 - (c)][0], csT[23 - (c)][1])
#define EXPV(q, M)      expv<M>(amp, W, q, acc)

__global__ __launch_bounds__(256, 2)   // R4: (256,4) capped VGPR at 64 -> 878 MB spill traffic
void qsim_kernel(const float* __restrict__ sv,      // [B, 4096]
                 const float* __restrict__ ang,     // [96]
                 const float* __restrict__ W,       // [10, 36]
                 const float* __restrict__ bvec,    // [10]
                 float* __restrict__ out)           // [B, 10]
{
    __shared__ F2    psi[DIM];       // 32 KB transpose buffer
    __shared__ float uT[24][8];      // fused Rz*Ry*Rx per (layer,qubit)
    __shared__ float csT[24][2];     // CRX (cos,sin); csT[12+g] is layer-1 tape slot g (ctrl=11-g)
    __shared__ float red[4][10];

    const int t = threadIdx.x;
    const int b = blockIdx.x;

    if (t < 24) {
        int l = t / 12, q = t % 12;
        build_u(ang[48*l + q], ang[48*l + 12 + q], ang[48*l + 24 + q], uT[t]);
    } else if (t >= 32 && t < 56) {
        int g = t - 32;
        float th = 0.5f * ang[g < 12 ? 36 + g : 72 + g];   // 84 + (g-12)
        csT[g][0] = cosf(th);
        csT[g][1] = sinf(th);
    }

    F2 amp[16];
    const float* svb = sv + (size_t)b * DIM;
#pragma unroll
    for (int r = 0; r < 16; ++r)                    // layout A, coalesced
        amp[r] = make_float2(svb[(r << 8) | t], 0.f);
    __syncthreads();                                // publish uT/csT

    float acc[10];
#pragma unroll
    for (int c = 0; c < 10; ++c) acc[c] = 0.f;

    // ---- A {0,1,2,3}: L0 1q on 0..3; L0 ring (0,1),(1,2),(2,3) ----
    U0(0, 8); U0(1, 4); U0(2, 2); U0(3, 1);
    CR0(0, 8, 4); CR0(1, 4, 2); CR0(2, 2, 1);
    XPOSE(addrA, addrB);

    // ---- B {3,4,5,6}: L0 1q on 4,5,6; L0 ring (3,4),(4,5),(5,6) ----
    U0(4, 4); U0(5, 2); U0(6, 1);
    CR0(3, 8, 4); CR0(4, 4, 2); CR0(5, 2, 1);
    XPOSE(addrB, addrC);

    // ---- C {6,7,8,9}: L0 1q on 7,8,9; L0 ring (6,7),(7,8),(8,9) ----
    U0(7, 4); U0(8, 2); U0(9, 1);
    CR0(6, 8, 4); CR0(7, 4, 2); CR0(8, 2, 1);
    XPOSE(addrC, addrD);

    // ---- DE {9,10,11,0} (q0->8, q9->4, q10->2, q11->1):
    //      L0 1q on 10,11; L0 ring (9,10),(10,11),(11,0);
    //      L1 1q on 9,10,11,0; L1 ring (11,0),(10,11),(9,10); expv 10,11 ----
    U0(10, 2); U0(11, 1);
    CR0(9, 4, 2); CR0(10, 2, 1); CR0(11, 1, 8);
    U1(9, 4); U1(10, 2); U1(11, 1); U1(0, 8);
    CR1(11, 1, 8); CR1(10, 2, 1); CR1(9, 4, 2);
    EXPV(10, 2); EXPV(11, 1);
    XPOSE(addrD, addrC);

    // ---- F {6,7,8,9}: L1 1q on 6,7,8; L1 ring (8,9),(7,8),(6,7); expv 7,8,9 ----
    U1(6, 8); U1(7, 4); U1(8, 2);
    CR1(8, 2, 1); CR1(7, 4, 2); CR1(6, 8, 4);
    EXPV(9, 1); EXPV(8, 2); EXPV(7, 4);
    XPOSE(addrC, addrB);

    // ---- G {3,4,5,6}: L1 1q on 3,4,5; L1 ring (5,6),(4,5),(3,4); expv 4,5,6 ----
    U1(3, 8); U1(4, 4); U1(5, 2);
    CR1(5, 2, 1); CR1(4, 4, 2); CR1(3, 8, 4);
    EXPV(6, 1); EXPV(5, 2); EXPV(4, 4);
    XPOSE(addrB, addrA);

    // ---- H {0,1,2,3}: L1 1q on 1,2; L1 ring (2,3),(1,2),(0,1); expv 0..3 ----
    U1(1, 4); U1(2, 2);
    CR1(2, 2, 1); CR1(1, 4, 2); CR1(0, 8, 4);
    EXPV(0, 8); EXPV(1, 4); EXPV(2, 2); EXPV(3, 1);

    // ---- reduce acc over wave, then over the 4 waves, add bias, store ----
#pragma unroll
    for (int c = 0; c < 10; ++c)
#pragma unroll
        for (int off = 32; off; off >>= 1) acc[c] += __shfl_xor(acc[c], off);
    const int lane = t & 63, w = t >> 6;
    if (lane == 0)
#pragma unroll
        for (int c = 0; c < 10; ++c) red[w][c] = acc[c];
    __syncthreads();
    if (t < 10)
        out[(size_t)b * 10 + t] = red[0][t] + red[1][t] + red[2][t] + red[3][t] + bvec[t];
}

extern "C" void kernel_launch(void* const* d_in, const int* in_sizes, int n_in,
                              void* d_out, int out_size, void* d_ws, size_t ws_size,
                              hipStream_t stream) {
    const float* sv     = (const float*)d_in[0];
    const float* angles = (const float*)d_in[1];
    const float* W      = (const float*)d_in[2];
    const float* bvec   = (const float*)d_in[3];
    float* out = (float*)d_out;
    int batch = in_sizes[0] / DIM;   // 2048
    qsim_kernel<<<batch, 256, 0, stream>>>(sv, angles, W, bvec, out);
}

// Round 6
// 182.214 us; speedup vs baseline: 2.8145x; 1.4258x over previous
//
#include <hip/hip_runtime.h>

#define DIM 4096
using F2 = float2;

// 256 threads/block, one block per batch element. 16 float2 amps per thread.
// Amplitude index a (12 bits): per-layout, 4 bits are "reg bits" (the r index,
// r bit3 -> highest of the quad's bit positions) and 8 bits are thread bits
// (t bit7 -> highest remaining position). Qubit q lives at bit (11-q).
// Layout A/H: quad {0,1,2,3}  -> bits {11,10,9,8}
// Layout B/G: quad {3,4,5,6}  -> bits {8,7,6,5}
// Layout C/F: quad {6,7,8,9}  -> bits {5,4,3,2}
// Layout DE : quad {9,10,11,0}-> bits {2,1,0,11}

__device__ __forceinline__ int swz(int i)            { return i ^ (i >> 6); }  // LDS anti-conflict
__device__ __forceinline__ int addrA(int r, int t)   { return (r << 8) | t; }
__device__ __forceinline__ int addrB(int r, int t)   { return ((t >> 5) << 9) | (r << 5) | (t & 31); }
__device__ __forceinline__ int addrC(int r, int t)   { return ((t >> 2) << 6) | (r << 2) | (t & 3); }
__device__ __forceinline__ int addrD(int r, int t)   { return ((r >> 3) << 11) | (t << 3) | (r & 7); }

__device__ __forceinline__ void build_u(float tx, float ty, float tz, float* u) {
    float sx = sinf(0.5f*tx), cx = cosf(0.5f*tx);
    float sy = sinf(0.5f*ty), cy = cosf(0.5f*ty);
    float sz = sinf(0.5f*tz), cz = cosf(0.5f*tz);
    float A00r = cy*cx, A00i =  sy*sx;     // A = Ry*Rx
    float A01r = -sy*cx, A01i = -cy*sx;
    float A10r =  sy*cx, A10i = -cy*sx;
    float A11r =  cy*cx, A11i = -sy*sx;
    // U = Rz*A: row0 *= (cz - i sz), row1 *= (cz + i sz)   [math verified rounds 1/3/4/5]
    u[0] = cz*A00r + sz*A00i;  u[1] = cz*A00i - sz*A00r;
    u[2] = cz*A01r + sz*A01i;  u[3] = cz*A01i - sz*A01r;
    u[4] = cz*A10r - sz*A10i;  u[5] = cz*A10i + sz*A10r;
    u[6] = cz*A11r - sz*A11i;  u[7] = cz*A11i + sz*A11r;
}

template<int M>  // fused 1q gate on reg-bit M pairs (compile-time)
__device__ __forceinline__ void g1q(F2* amp, const float* u) {
    float u0=u[0],u1=u[1],u2=u[2],u3=u[3],u4=u[4],u5=u[5],u6=u[6],u7=u[7];
#pragma unroll
    for (int r0 = 0; r0 < 16; ++r0) {
        if (r0 & M) continue;
        const int r1 = r0 + M;
        F2 a0 = amp[r0], a1 = amp[r1];
        amp[r0].x = u0*a0.x - u1*a0.y + u2*a1.x - u3*a1.y;
        amp[r0].y = u0*a0.y + u1*a0.x + u2*a1.y + u3*a1.x;
        amp[r1].x = u4*a0.x - u5*a0.y + u6*a1.x - u7*a1.y;
        amp[r1].y = u4*a0.y + u5*a0.x + u6*a1.y + u7*a1.x;
    }
}

template<int MC, int MT>  // CRX: control reg bit MC (=1), RX on target reg bit MT
__device__ __forceinline__ void crx(F2* amp, float cc, float ss) {
#pragma unroll
    for (int r0 = 0; r0 < 16; ++r0) {
        if (!(r0 & MC) || (r0 & MT)) continue;
        const int r1 = r0 + MT;
        F2 a0 = amp[r0], a1 = amp[r1];
        amp[r0] = make_float2(cc*a0.x + ss*a1.y, cc*a0.y - ss*a1.x);
        amp[r1] = make_float2(ss*a0.y + cc*a1.x, -ss*a0.x + cc*a1.y);
    }
}

template<int M>  // <X_q>,<Y_q>,<Z_q>: wave-reduce immediately, park in LDS (no live acc)
__device__ __forceinline__ void expv(const F2* amp, int q, int lane, int w,
                                     float fred[4][36]) {
    float xr = 0.f, xi = 0.f, zz = 0.f;
#pragma unroll
    for (int r0 = 0; r0 < 16; ++r0) {
        if (r0 & M) continue;
        const int r1 = r0 + M;
        F2 a0 = amp[r0], a1 = amp[r1];
        zz += a0.x*a0.x + a0.y*a0.y - a1.x*a1.x - a1.y*a1.y;
        xr += a0.x*a1.x + a0.y*a1.y;   // Re(conj(a0)*a1)
        xi += a0.x*a1.y - a0.y*a1.x;   // Im(conj(a0)*a1)
    }
    xr *= 2.f; xi *= 2.f;              // X=2ReS, Y=2ImS; pairs disjoint across threads
#pragma unroll
    for (int off = 32; off; off >>= 1) {
        xr += __shfl_xor(xr, off);
        xi += __shfl_xor(xi, off);
        zz += __shfl_xor(zz, off);
    }
    if (lane == 0) { fred[w][q] = xr; fred[w][12 + q] = xi; fred[w][24 + q] = zz; }
}

#define XPOSE(CUR, NXT) \
  { _Pragma("unroll") for (int r = 0; r < 16; ++r) psi[swz(CUR(r, t))] = amp[r]; \
    __syncthreads(); \
    _Pragma("unroll") for (int r = 0; r < 16; ++r) amp[r] = psi[swz(NXT(r, t))]; \
    __syncthreads(); }

#define U0(q, M)        g1q<M>(amp, uT[q])
#define U1(q, M)        g1q<M>(amp, uT[12 + (q)])
#define CR0(c, MC, MT)  crx<MC, MT>(amp, csT[c][0], csT[c][1])
#define CR1(c, MC, MT)  crx<MC, MT>(amp, csT[23 - (c)][0], csT[23 - (c)][1])
#define EXPV(q, M)      expv<M>(amp, q, lane, w, fred)

// R4: (256,4) capped VGPR at 64 -> 878 MB spill. R5: (256,2) clamped at 128, still
// 127 MB spill. (256,1): no clamp; acc[10] removed so true need is low anyway.
__global__ __launch_bounds__(256, 1)
void qsim_kernel(const float* __restrict__ sv,      // [B, 4096]
                 const float* __restrict__ ang,     // [96]
                 const float* __restrict__ W,       // [10, 36]
                 const float* __restrict__ bvec,    // [10]
                 float* __restrict__ out)           // [B, 10]
{
    __shared__ F2    psi[DIM];       // 32 KB transpose buffer
    __shared__ float uT[24][8];      // fused Rz*Ry*Rx per (layer,qubit)
    __shared__ float csT[24][2];     // CRX (cos,sin); csT[12+g] is layer-1 tape slot g
    __shared__ float fred[4][36];    // per-wave reduced features
    __shared__ float fsum[36];

    const int t = threadIdx.x;
    const int b = blockIdx.x;
    const int lane = t & 63, w = t >> 6;

    if (t < 24) {
        int l = t / 12, q = t % 12;
        build_u(ang[48*l + q], ang[48*l + 12 + q], ang[48*l + 24 + q], uT[t]);
    } else if (t >= 32 && t < 56) {
        int g = t - 32;
        float th = 0.5f * ang[g < 12 ? 36 + g : 72 + g];   // 84 + (g-12)
        csT[g][0] = cosf(th);
        csT[g][1] = sinf(th);
    }

    F2 amp[16];
    const float* svb = sv + (size_t)b * DIM;
#pragma unroll
    for (int r = 0; r < 16; ++r)                    // layout A, coalesced
        amp[r] = make_float2(svb[(r << 8) | t], 0.f);
    __syncthreads();                                // publish uT/csT

    // ---- A {0,1,2,3}: L0 1q on 0..3; L0 ring (0,1),(1,2),(2,3) ----
    U0(0, 8); U0(1, 4); U0(2, 2); U0(3, 1);
    CR0(0, 8, 4); CR0(1, 4, 2); CR0(2, 2, 1);
    XPOSE(addrA, addrB);

    // ---- B {3,4,5,6}: L0 1q on 4,5,6; L0 ring (3,4),(4,5),(5,6) ----
    U0(4, 4); U0(5, 2); U0(6, 1);
    CR0(3, 8, 4); CR0(4, 4, 2); CR0(5, 2, 1);
    XPOSE(addrB, addrC);

    // ---- C {6,7,8,9}: L0 1q on 7,8,9; L0 ring (6,7),(7,8),(8,9) ----
    U0(7, 4); U0(8, 2); U0(9, 1);
    CR0(6, 8, 4); CR0(7, 4, 2); CR0(8, 2, 1);
    XPOSE(addrC, addrD);

    // ---- DE {9,10,11,0} (q0->8, q9->4, q10->2, q11->1):
    //      L0 1q on 10,11; L0 ring (9,10),(10,11),(11,0);
    //      L1 1q on 9,10,11,0; L1 ring (11,0),(10,11),(9,10); expv 10,11 ----
    U0(10, 2); U0(11, 1);
    CR0(9, 4, 2); CR0(10, 2, 1); CR0(11, 1, 8);
    U1(9, 4); U1(10, 2); U1(11, 1); U1(0, 8);
    CR1(11, 1, 8); CR1(10, 2, 1); CR1(9, 4, 2);
    EXPV(10, 2); EXPV(11, 1);
    XPOSE(addrD, addrC);

    // ---- F {6,7,8,9}: L1 1q on 6,7,8; L1 ring (8,9),(7,8),(6,7); expv 7,8,9 ----
    U1(6, 8); U1(7, 4); U1(8, 2);
    CR1(8, 2, 1); CR1(7, 4, 2); CR1(6, 8, 4);
    EXPV(9, 1); EXPV(8, 2); EXPV(7, 4);
    XPOSE(addrC, addrB);

    // ---- G {3,4,5,6}: L1 1q on 3,4,5; L1 ring (5,6),(4,5),(3,4); expv 4,5,6 ----
    U1(3, 8); U1(4, 4); U1(5, 2);
    CR1(5, 2, 1); CR1(4, 4, 2); CR1(3, 8, 4);
    EXPV(6, 1); EXPV(5, 2); EXPV(4, 4);
    XPOSE(addrB, addrA);

    // ---- H {0,1,2,3}: L1 1q on 1,2; L1 ring (2,3),(1,2),(0,1); expv 0..3 ----
    U1(1, 4); U1(2, 2);
    CR1(2, 2, 1); CR1(1, 4, 2); CR1(0, 8, 4);
    EXPV(0, 8); EXPV(1, 4); EXPV(2, 2); EXPV(3, 1);

    // ---- combine the 4 per-wave feature sets, apply 10x36 head, store ----
    __syncthreads();
    if (t < 36) fsum[t] = fred[0][t] + fred[1][t] + fred[2][t] + fred[3][t];
    __syncthreads();
    if (t < 10) {
        float a = bvec[t];
#pragma unroll
        for (int f = 0; f < 36; ++f) a += fsum[f] * W[t * 36 + f];
        out[(size_t)b * 10 + t] = a;
    }
}

extern "C" void kernel_launch(void* const* d_in, const int* in_sizes, int n_in,
                              void* d_out, int out_size, void* d_ws, size_t ws_size,
                              hipStream_t stream) {
    const float* sv     = (const float*)d_in[0];
    const float* angles = (const float*)d_in[1];
    const float* W      = (const float*)d_in[2];
    const float* bvec   = (const float*)d_in[3];
    float* out = (float*)d_out;
    int batch = in_sizes[0] / DIM;   // 2048
    qsim_kernel<<<batch, 256, 0, stream>>>(sv, angles, W, bvec, out);
}

// Round 7
// 163.122 us; speedup vs baseline: 3.1439x; 1.1170x over previous
//
#include <hip/hip_runtime.h>

#define DIM 4096
using F2 = float2;

// 256 threads/block, one block per batch element. 16 float2 amps per thread.
// Amplitude index a (12 bits): per-layout, 4 bits are "reg bits" (the r index,
// r bit3 -> highest of the quad's bit positions) and 8 bits are thread bits
// (t bit7 -> highest remaining position). Qubit q lives at bit (11-q).
// Layout A/H: quad {0,1,2,3}  -> bits {11,10,9,8}
// Layout B/G: quad {3,4,5,6}  -> bits {8,7,6,5}
// Layout C/F: quad {6,7,8,9}  -> bits {5,4,3,2}
// Layout DE : quad {9,10,11,0}-> bits {2,1,0,11}

__device__ __forceinline__ int swz(int i)            { return i ^ (i >> 6); }  // LDS anti-conflict
__device__ __forceinline__ int addrA(int r, int t)   { return (r << 8) | t; }
__device__ __forceinline__ int addrB(int r, int t)   { return ((t >> 5) << 9) | (r << 5) | (t & 31); }
__device__ __forceinline__ int addrC(int r, int t)   { return ((t >> 2) << 6) | (r << 2) | (t & 3); }
__device__ __forceinline__ int addrD(int r, int t)   { return ((r >> 3) << 11) | (t << 3) | (r & 7); }

__device__ __forceinline__ void build_u(float tx, float ty, float tz, float* u) {
    float sx = sinf(0.5f*tx), cx = cosf(0.5f*tx);
    float sy = sinf(0.5f*ty), cy = cosf(0.5f*ty);
    float sz = sinf(0.5f*tz), cz = cosf(0.5f*tz);
    float A00r = cy*cx, A00i =  sy*sx;     // A = Ry*Rx
    float A01r = -sy*cx, A01i = -cy*sx;
    float A10r =  sy*cx, A10i = -cy*sx;
    float A11r =  cy*cx, A11i = -sy*sx;
    // U = Rz*A: row0 *= (cz - i sz), row1 *= (cz + i sz)   [math verified r1/3/4/5/6]
    u[0] = cz*A00r + sz*A00i;  u[1] = cz*A00i - sz*A00r;
    u[2] = cz*A01r + sz*A01i;  u[3] = cz*A01i - sz*A01r;
    u[4] = cz*A10r - sz*A10i;  u[5] = cz*A10i + sz*A10r;
    u[6] = cz*A11r - sz*A11i;  u[7] = cz*A11i + sz*A11r;
}

// coef layout in d_ws: [0..191] = 24 fused-1q gates x 8 floats (layer*12+q)
//                      [192..239] = 24 CRX x (cos,sin); slot 12+g = layer-1 tape g
__global__ void prep_kernel(const float* __restrict__ ang, float* __restrict__ coef) {
    int t = threadIdx.x;
    if (t < 24) {
        int l = t / 12, q = t % 12;
        float u[8];
        build_u(ang[48*l + q], ang[48*l + 12 + q], ang[48*l + 24 + q], u);
#pragma unroll
        for (int j = 0; j < 8; ++j) coef[t * 8 + j] = u[j];
    } else if (t < 48) {
        int g = t - 24;
        float th = 0.5f * ang[g < 12 ? 36 + g : 72 + g];   // 84 + (g-12)
        coef[192 + g * 2]     = cosf(th);
        coef[192 + g * 2 + 1] = sinf(th);
    }
}

template<int M>  // fused 1q gate on reg-bit M pairs; u = uniform (scalar-loaded) coeffs
__device__ __forceinline__ void g1q(F2* amp, const float* __restrict__ u) {
    float u0=u[0],u1=u[1],u2=u[2],u3=u[3],u4=u[4],u5=u[5],u6=u[6],u7=u[7];
#pragma unroll
    for (int r0 = 0; r0 < 16; ++r0) {
        if (r0 & M) continue;
        const int r1 = r0 + M;
        F2 a0 = amp[r0], a1 = amp[r1];
        amp[r0].x = u0*a0.x - u1*a0.y + u2*a1.x - u3*a1.y;
        amp[r0].y = u0*a0.y + u1*a0.x + u2*a1.y + u3*a1.x;
        amp[r1].x = u4*a0.x - u5*a0.y + u6*a1.x - u7*a1.y;
        amp[r1].y = u4*a0.y + u5*a0.x + u6*a1.y + u7*a1.x;
    }
}

template<int MC, int MT>  // CRX: control reg bit MC (=1), RX on target reg bit MT
__device__ __forceinline__ void crx(F2* amp, float cc, float ss) {
#pragma unroll
    for (int r0 = 0; r0 < 16; ++r0) {
        if (!(r0 & MC) || (r0 & MT)) continue;
        const int r1 = r0 + MT;
        F2 a0 = amp[r0], a1 = amp[r1];
        amp[r0] = make_float2(cc*a0.x + ss*a1.y, cc*a0.y - ss*a1.x);
        amp[r1] = make_float2(ss*a0.y + cc*a1.x, -ss*a0.x + cc*a1.y);
    }
}

template<int M>  // wave-reduce <X_q>,<Y_q>,<Z_q>; park totals in lane q's registers
__device__ __forceinline__ void expv(const F2* amp, int q, int lane,
                                     float& fx, float& fy, float& fz) {
    float xr = 0.f, xi = 0.f, zz = 0.f;
#pragma unroll
    for (int r0 = 0; r0 < 16; ++r0) {
        if (r0 & M) continue;
        const int r1 = r0 + M;
        F2 a0 = amp[r0], a1 = amp[r1];
        zz += a0.x*a0.x + a0.y*a0.y - a1.x*a1.x - a1.y*a1.y;
        xr += a0.x*a1.x + a0.y*a1.y;   // Re(conj(a0)*a1)
        xi += a0.x*a1.y - a0.y*a1.x;   // Im(conj(a0)*a1)
    }
    xr *= 2.f; xi *= 2.f;              // X=2ReS, Y=2ImS; pairs disjoint across threads
#pragma unroll
    for (int off = 32; off; off >>= 1) {
        xr += __shfl_xor(xr, off);
        xi += __shfl_xor(xi, off);
        zz += __shfl_xor(zz, off);
    }
    if (lane == q) { fx = xr; fy = xi; fz = zz; }   // cndmask, no divergence
}

#define XPOSE(CUR, NXT) \
  { _Pragma("unroll") for (int r = 0; r < 16; ++r) psi[swz(CUR(r, t))] = amp[r]; \
    __syncthreads(); \
    _Pragma("unroll") for (int r = 0; r < 16; ++r) amp[r] = psi[swz(NXT(r, t))]; \
    __syncthreads(); }

#define U0(q, M)        g1q<M>(amp, cf + (q) * 8)
#define U1(q, M)        g1q<M>(amp, cf + (12 + (q)) * 8)
#define CR0(c, MC, MT)  crx<MC, MT>(amp, cf[192 + (c)*2], cf[192 + (c)*2 + 1])
#define CR1(c, MC, MT)  crx<MC, MT>(amp, cf[192 + (23-(c))*2], cf[192 + (23-(c))*2 + 1])
#define EXPV(q, M)      expv<M>(amp, q, lane, fx, fy, fz)

// R4: (256,4)->64 VGPR cap = 878MB spill. R5: (256,2)->128 clamp, 127MB spill.
// R6: (256,1), 104 VGPR, no spill. R7: coeffs via s_load, LDS=32KB -> 5 blocks/CU.
__global__ __launch_bounds__(256, 1)
void qsim_kernel(const float* __restrict__ sv,      // [B, 4096]
                 const float* __restrict__ cf,      // [240] precomputed coefficients
                 const float* __restrict__ W,       // [10, 36]
                 const float* __restrict__ bvec,    // [10]
                 float* __restrict__ out)           // [B, 10]
{
    __shared__ F2 psi[DIM];          // exactly 32 KB -> 5 blocks/CU
    const int t = threadIdx.x;
    const int b = blockIdx.x;
    const int lane = t & 63, w = t >> 6;

    F2 amp[16];
    const float* svb = sv + (size_t)b * DIM;
#pragma unroll
    for (int r = 0; r < 16; ++r)                    // layout A, coalesced
        amp[r] = make_float2(svb[(r << 8) | t], 0.f);

    float fx = 0.f, fy = 0.f, fz = 0.f;             // per-lane feature slots

    // ---- A {0,1,2,3}: L0 1q on 0..3; L0 ring (0,1),(1,2),(2,3) ----
    U0(0, 8); U0(1, 4); U0(2, 2); U0(3, 1);
    CR0(0, 8, 4); CR0(1, 4, 2); CR0(2, 2, 1);
    XPOSE(addrA, addrB);

    // ---- B {3,4,5,6}: L0 1q on 4,5,6; L0 ring (3,4),(4,5),(5,6) ----
    U0(4, 4); U0(5, 2); U0(6, 1);
    CR0(3, 8, 4); CR0(4, 4, 2); CR0(5, 2, 1);
    XPOSE(addrB, addrC);

    // ---- C {6,7,8,9}: L0 1q on 7,8,9; L0 ring (6,7),(7,8),(8,9) ----
    U0(7, 4); U0(8, 2); U0(9, 1);
    CR0(6, 8, 4); CR0(7, 4, 2); CR0(8, 2, 1);
    XPOSE(addrC, addrD);

    // ---- DE {9,10,11,0} (q0->8, q9->4, q10->2, q11->1):
    //      L0 1q on 10,11; L0 ring (9,10),(10,11),(11,0);
    //      L1 1q on 9,10,11,0; L1 ring (11,0),(10,11),(9,10); expv 10,11 ----
    U0(10, 2); U0(11, 1);
    CR0(9, 4, 2); CR0(10, 2, 1); CR0(11, 1, 8);
    U1(9, 4); U1(10, 2); U1(11, 1); U1(0, 8);
    CR1(11, 1, 8); CR1(10, 2, 1); CR1(9, 4, 2);
    EXPV(10, 2); EXPV(11, 1);
    XPOSE(addrD, addrC);

    // ---- F {6,7,8,9}: L1 1q on 6,7,8; L1 ring (8,9),(7,8),(6,7); expv 7,8,9 ----
    U1(6, 8); U1(7, 4); U1(8, 2);
    CR1(8, 2, 1); CR1(7, 4, 2); CR1(6, 8, 4);
    EXPV(9, 1); EXPV(8, 2); EXPV(7, 4);
    XPOSE(addrC, addrB);

    // ---- G {3,4,5,6}: L1 1q on 3,4,5; L1 ring (5,6),(4,5),(3,4); expv 4,5,6 ----
    U1(3, 8); U1(4, 4); U1(5, 2);
    CR1(5, 2, 1); CR1(4, 4, 2); CR1(3, 8, 4);
    EXPV(6, 1); EXPV(5, 2); EXPV(4, 4);
    XPOSE(addrB, addrA);

    // ---- H {0,1,2,3}: L1 1q on 1,2; L1 ring (2,3),(1,2),(0,1); expv 0..3 ----
    U1(1, 4); U1(2, 2);
    CR1(2, 2, 1); CR1(1, 4, 2); CR1(0, 8, 4);
    EXPV(0, 8); EXPV(1, 4); EXPV(2, 2); EXPV(3, 1);

    // ---- combine per-wave features (psi is dead after last XPOSE: alias it) ----
    float* fbuf = (float*)psi;       // [4][36]
    if (lane < 12) {
        fbuf[w * 36 + lane]      = fx;
        fbuf[w * 36 + 12 + lane] = fy;
        fbuf[w * 36 + 24 + lane] = fz;
    }
    __syncthreads();
    if (t < 10) {
        float a = bvec[t];
#pragma unroll
        for (int f = 0; f < 36; ++f)
            a += W[t * 36 + f] * (fbuf[f] + fbuf[36 + f] + fbuf[72 + f] + fbuf[108 + f]);
        out[(size_t)b * 10 + t] = a;
    }
}

extern "C" void kernel_launch(void* const* d_in, const int* in_sizes, int n_in,
                              void* d_out, int out_size, void* d_ws, size_t ws_size,
                              hipStream_t stream) {
    const float* sv     = (const float*)d_in[0];
    const float* angles = (const float*)d_in[1];
    const float* W      = (const float*)d_in[2];
    const float* bvec   = (const float*)d_in[3];
    float* out  = (float*)d_out;
    float* coef = (float*)d_ws;      // 240 floats of scratch
    int batch = in_sizes[0] / DIM;   // 2048
    prep_kernel<<<1, 64, 0, stream>>>(angles, coef);
    qsim_kernel<<<batch, 256, 0, stream>>>(sv, coef, W, bvec, out);
}

// Round 8
// 141.167 us; speedup vs baseline: 3.6329x; 1.1555x over previous
//
#include <hip/hip_runtime.h>

#define DIM 4096
using F2 = float2;

// 256 threads/block, one block per batch element. 16 float2 amps per thread.
// Layouts/schedule identical to R7 (passed, absmax 1.2e-4). R8 change: all gate
// arithmetic uses packed fp32 (v_pk_fma_f32 / v_pk_mul_f32) -- one instruction
// per two scalar FMAs; complex mul = broadcast-lo mul + swapped-hi cross FMA.
// Layout A/H: quad {0,1,2,3}  -> bits {11,10,9,8}
// Layout B/G: quad {3,4,5,6}  -> bits {8,7,6,5}
// Layout C/F: quad {6,7,8,9}  -> bits {5,4,3,2}
// Layout DE : quad {9,10,11,0}-> bits {2,1,0,11}

__device__ __forceinline__ int swz(int i)            { return i ^ (i >> 6); }
__device__ __forceinline__ int addrA(int r, int t)   { return (r << 8) | t; }
__device__ __forceinline__ int addrB(int r, int t)   { return ((t >> 5) << 9) | (r << 5) | (t & 31); }
__device__ __forceinline__ int addrC(int r, int t)   { return ((t >> 2) << 6) | (r << 2) | (t & 3); }
__device__ __forceinline__ int addrD(int r, int t)   { return ((r >> 3) << 11) | (t << 3) | (r & 7); }

// ---- packed fp32 complex primitives (VOP3P) ----
// d = (a.x*u.x, a.y*u.x)   [broadcast u.lo]
__device__ __forceinline__ F2 pk_mul_bl(F2 a, F2 u) {
    F2 d;
    asm("v_pk_mul_f32 %0, %1, %2 op_sel:[0,0] op_sel_hi:[1,0]"
        : "=v"(d) : "v"(a), "v"(u));
    return d;
}
// d += (-a.y*u.y, a.x*u.y)   [complex cross term of u*a]
__device__ __forceinline__ void pk_cross(F2& d, F2 a, F2 u) {
    asm("v_pk_fma_f32 %0, %1, %2, %0 op_sel:[1,1,0] op_sel_hi:[0,1,1] neg_lo:[1,0,0]"
        : "+v"(d) : "v"(a), "v"(u));
}
// d += (a.x*u.x, a.y*u.x)   [broadcast u.lo FMA]
__device__ __forceinline__ void pk_fma_bl(F2& d, F2 a, F2 u) {
    asm("v_pk_fma_f32 %0, %1, %2, %0 op_sel:[0,0,0] op_sel_hi:[1,0,1]"
        : "+v"(d) : "v"(a), "v"(u));
}
// d += (a.y*cs.y, -a.x*cs.y)   [CRX cross term: s * (swap, neg-hi)]
__device__ __forceinline__ void pk_swapneg(F2& d, F2 a, F2 cs) {
    asm("v_pk_fma_f32 %0, %1, %2, %0 op_sel:[1,1,0] op_sel_hi:[0,1,1] neg_hi:[1,0,0]"
        : "+v"(d) : "v"(a), "v"(cs));
}
// d += a*b (plain packed)
__device__ __forceinline__ void pk_fma(F2& d, F2 a, F2 b) {
    asm("v_pk_fma_f32 %0, %1, %2, %0" : "+v"(d) : "v"(a), "v"(b));
}
// d += (a0.x*a1.y, -a0.y*a1.x)   [Im(conj(a0)*a1) parts]
__device__ __forceinline__ void pk_imacc(F2& d, F2 a0, F2 a1) {
    asm("v_pk_fma_f32 %0, %1, %2, %0 op_sel:[0,1,0] op_sel_hi:[1,0,1] neg_hi:[1,0,0]"
        : "+v"(d) : "v"(a0), "v"(a1));
}
// d = U*a (complex)
__device__ __forceinline__ F2 pk_cmul(F2 u, F2 a) {
    F2 d = pk_mul_bl(a, u);
    pk_cross(d, a, u);
    return d;
}
// d += U*a (complex)
__device__ __forceinline__ void pk_cfma(F2& d, F2 u, F2 a) {
    pk_fma_bl(d, a, u);
    pk_cross(d, a, u);
}

__device__ __forceinline__ void build_u(float tx, float ty, float tz, float* u) {
    float sx = sinf(0.5f*tx), cx = cosf(0.5f*tx);
    float sy = sinf(0.5f*ty), cy = cosf(0.5f*ty);
    float sz = sinf(0.5f*tz), cz = cosf(0.5f*tz);
    float A00r = cy*cx, A00i =  sy*sx;     // A = Ry*Rx
    float A01r = -sy*cx, A01i = -cy*sx;
    float A10r =  sy*cx, A10i = -cy*sx;
    float A11r =  cy*cx, A11i = -sy*sx;
    // U = Rz*A: row0 *= (cz - i sz), row1 *= (cz + i sz)   [verified r1/3/5/6/7]
    u[0] = cz*A00r + sz*A00i;  u[1] = cz*A00i - sz*A00r;
    u[2] = cz*A01r + sz*A01i;  u[3] = cz*A01i - sz*A01r;
    u[4] = cz*A10r - sz*A10i;  u[5] = cz*A10i + sz*A10r;
    u[6] = cz*A11r - sz*A11i;  u[7] = cz*A11i + sz*A11r;
}

// coef layout in d_ws: [0..191] = 24 fused-1q gates x 8 floats (layer*12+q)
//                      [192..239] = 24 CRX x (cos,sin); slot 12+g = layer-1 tape g
__global__ void prep_kernel(const float* __restrict__ ang, float* __restrict__ coef) {
    int t = threadIdx.x;
    if (t < 24) {
        int l = t / 12, q = t % 12;
        float u[8];
        build_u(ang[48*l + q], ang[48*l + 12 + q], ang[48*l + 24 + q], u);
#pragma unroll
        for (int j = 0; j < 8; ++j) coef[t * 8 + j] = u[j];
    } else if (t < 48) {
        int g = t - 24;
        float th = 0.5f * ang[g < 12 ? 36 + g : 72 + g];   // 84 + (g-12)
        coef[192 + g * 2]     = cosf(th);
        coef[192 + g * 2 + 1] = sinf(th);
    }
}

template<int M>  // fused 1q gate on reg-bit M pairs; packed complex math
__device__ __forceinline__ void g1q(F2* amp, const float* __restrict__ u) {
    F2 u00 = {u[0], u[1]}, u01 = {u[2], u[3]};
    F2 u10 = {u[4], u[5]}, u11 = {u[6], u[7]};
#pragma unroll
    for (int r0 = 0; r0 < 16; ++r0) {
        if (r0 & M) continue;
        const int r1 = r0 + M;
        F2 a0 = amp[r0], a1 = amp[r1];
        F2 n0 = pk_cmul(u00, a0); pk_cfma(n0, u01, a1);
        F2 n1 = pk_cmul(u10, a0); pk_cfma(n1, u11, a1);
        amp[r0] = n0; amp[r1] = n1;
    }
}

template<int MC, int MT>  // CRX: ctrl reg bit MC (=1), RX on target reg bit MT
__device__ __forceinline__ void crx(F2* amp, F2 cs) {
#pragma unroll
    for (int r0 = 0; r0 < 16; ++r0) {
        if (!(r0 & MC) || (r0 & MT)) continue;
        const int r1 = r0 + MT;
        F2 a0 = amp[r0], a1 = amp[r1];
        // n0 = (c*a0.x + s*a1.y, c*a0.y - s*a1.x); n1 = (c*a1.x + s*a0.y, c*a1.y - s*a0.x)
        F2 n0 = pk_mul_bl(a0, cs); pk_swapneg(n0, a1, cs);
        F2 n1 = pk_mul_bl(a1, cs); pk_swapneg(n1, a0, cs);
        amp[r0] = n0; amp[r1] = n1;
    }
}

template<int M>  // wave-reduce <X_q>,<Y_q>,<Z_q>; park totals in lane q's registers
__device__ __forceinline__ void expv(const F2* amp, int q, int lane,
                                     float& fx, float& fy, float& fz) {
    F2 zp = {0.f, 0.f}, zm = {0.f, 0.f}, xp = {0.f, 0.f}, ip = {0.f, 0.f};
#pragma unroll
    for (int r0 = 0; r0 < 16; ++r0) {
        if (r0 & M) continue;
        const int r1 = r0 + M;
        F2 a0 = amp[r0], a1 = amp[r1];
        pk_fma(zp, a0, a0);        // |a0|^2 parts
        pk_fma(zm, a1, a1);        // |a1|^2 parts
        pk_fma(xp, a0, a1);        // Re(conj(a0)*a1) parts
        pk_imacc(ip, a0, a1);      // Im(conj(a0)*a1) parts
    }
    float zz = (zp.x + zp.y) - (zm.x + zm.y);
    float xr = 2.f * (xp.x + xp.y);
    float xi = 2.f * (ip.x + ip.y);
#pragma unroll
    for (int off = 32; off; off >>= 1) {
        xr += __shfl_xor(xr, off);
        xi += __shfl_xor(xi, off);
        zz += __shfl_xor(zz, off);
    }
    if (lane == q) { fx = xr; fy = xi; fz = zz; }
}

#define XPOSE(CUR, NXT) \
  { _Pragma("unroll") for (int r = 0; r < 16; ++r) psi[swz(CUR(r, t))] = amp[r]; \
    __syncthreads(); \
    _Pragma("unroll") for (int r = 0; r < 16; ++r) amp[r] = psi[swz(NXT(r, t))]; \
    __syncthreads(); }

#define U0(q, M)        g1q<M>(amp, cf + (q) * 8)
#define U1(q, M)        g1q<M>(amp, cf + (12 + (q)) * 8)
#define CR0(c, MC, MT)  crx<MC, MT>(amp, F2{cf[192 + (c)*2], cf[192 + (c)*2 + 1]})
#define CR1(c, MC, MT)  crx<MC, MT>(amp, F2{cf[192 + (23-(c))*2], cf[192 + (23-(c))*2 + 1]})
#define EXPV(q, M)      expv<M>(amp, q, lane, fx, fy, fz)

// R4: (256,4) VGPR=64 -> 878MB spill. R5: (256,2) 128 clamp, 127MB spill.
// R6: (256,1) 104 VGPR no spill. R7: s_load coeffs, 32KB LDS. R8: packed fp32.
__global__ __launch_bounds__(256, 1)
void qsim_kernel(const float* __restrict__ sv,      // [B, 4096]
                 const float* __restrict__ cf,      // [240] precomputed coefficients
                 const float* __restrict__ W,       // [10, 36]
                 const float* __restrict__ bvec,    // [10]
                 float* __restrict__ out)           // [B, 10]
{
    __shared__ F2 psi[DIM];          // exactly 32 KB
    const int t = threadIdx.x;
    const int b = blockIdx.x;
    const int lane = t & 63, w = t >> 6;

    F2 amp[16];
    const float* svb = sv + (size_t)b * DIM;
#pragma unroll
    for (int r = 0; r < 16; ++r)                    // layout A, coalesced
        amp[r] = make_float2(svb[(r << 8) | t], 0.f);

    float fx = 0.f, fy = 0.f, fz = 0.f;             // per-lane feature slots

    // ---- A {0,1,2,3}: L0 1q on 0..3; L0 ring (0,1),(1,2),(2,3) ----
    U0(0, 8); U0(1, 4); U0(2, 2); U0(3, 1);
    CR0(0, 8, 4); CR0(1, 4, 2); CR0(2, 2, 1);
    XPOSE(addrA, addrB);

    // ---- B {3,4,5,6}: L0 1q on 4,5,6; L0 ring (3,4),(4,5),(5,6) ----
    U0(4, 4); U0(5, 2); U0(6, 1);
    CR0(3, 8, 4); CR0(4, 4, 2); CR0(5, 2, 1);
    XPOSE(addrB, addrC);

    // ---- C {6,7,8,9}: L0 1q on 7,8,9; L0 ring (6,7),(7,8),(8,9) ----
    U0(7, 4); U0(8, 2); U0(9, 1);
    CR0(6, 8, 4); CR0(7, 4, 2); CR0(8, 2, 1);
    XPOSE(addrC, addrD);

    // ---- DE {9,10,11,0} (q0->8, q9->4, q10->2, q11->1):
    //      L0 1q on 10,11; L0 ring (9,10),(10,11),(11,0);
    //      L1 1q on 9,10,11,0; L1 ring (11,0),(10,11),(9,10); expv 10,11 ----
    U0(10, 2); U0(11, 1);
    CR0(9, 4, 2); CR0(10, 2, 1); CR0(11, 1, 8);
    U1(9, 4); U1(10, 2); U1(11, 1); U1(0, 8);
    CR1(11, 1, 8); CR1(10, 2, 1); CR1(9, 4, 2);
    EXPV(10, 2); EXPV(11, 1);
    XPOSE(addrD, addrC);

    // ---- F {6,7,8,9}: L1 1q on 6,7,8; L1 ring (8,9),(7,8),(6,7); expv 7,8,9 ----
    U1(6, 8); U1(7, 4); U1(8, 2);
    CR1(8, 2, 1); CR1(7, 4, 2); CR1(6, 8, 4);
    EXPV(9, 1); EXPV(8, 2); EXPV(7, 4);
    XPOSE(addrC, addrB);

    // ---- G {3,4,5,6}: L1 1q on 3,4,5; L1 ring (5,6),(4,5),(3,4); expv 4,5,6 ----
    U1(3, 8); U1(4, 4); U1(5, 2);
    CR1(5, 2, 1); CR1(4, 4, 2); CR1(3, 8, 4);
    EXPV(6, 1); EXPV(5, 2); EXPV(4, 4);
    XPOSE(addrB, addrA);

    // ---- H {0,1,2,3}: L1 1q on 1,2; L1 ring (2,3),(1,2),(0,1); expv 0..3 ----
    U1(1, 4); U1(2, 2);
    CR1(2, 2, 1); CR1(1, 4, 2); CR1(0, 8, 4);
    EXPV(0, 8); EXPV(1, 4); EXPV(2, 2); EXPV(3, 1);

    // ---- combine per-wave features (psi dead after last XPOSE: alias it) ----
    float* fbuf = (float*)psi;       // [4][36]
    if (lane < 12) {
        fbuf[w * 36 + lane]      = fx;
        fbuf[w * 36 + 12 + lane] = fy;
        fbuf[w * 36 + 24 + lane] = fz;
    }
    __syncthreads();
    if (t < 10) {
        float a = bvec[t];
#pragma unroll
        for (int f = 0; f < 36; ++f)
            a += W[t * 36 + f] * (fbuf[f] + fbuf[36 + f] + fbuf[72 + f] + fbuf[108 + f]);
        out[(size_t)b * 10 + t] = a;
    }
}

extern "C" void kernel_launch(void* const* d_in, const int* in_sizes, int n_in,
                              void* d_out, int out_size, void* d_ws, size_t ws_size,
                              hipStream_t stream) {
    const float* sv     = (const float*)d_in[0];
    const float* angles = (const float*)d_in[1];
    const float* W      = (const float*)d_in[2];
    const float* bvec   = (const float*)d_in[3];
    float* out  = (float*)d_out;
    float* coef = (float*)d_ws;      // 240 floats of scratch
    int batch = in_sizes[0] / DIM;   // 2048
    prep_kernel<<<1, 64, 0, stream>>>(angles, coef);
    qsim_kernel<<<batch, 256, 0, stream>>>(sv, coef, W, bvec, out);
}

// Round 9
// 135.703 us; speedup vs baseline: 3.7792x; 1.0403x over previous
//
#include <hip/hip_runtime.h>

#define DIM 4096
using F2 = float2;

// R9: 128 threads/block (2 waves), 32 F2 amps/thread, 5-bit reg groups.
// 5 phases / 4 LDS transposes (was 7/6); L0 CRX ring fused into 1q gates
// via compile-time-selected RX*U matrices. Qubit q lives at amp bit (11-q).
// Layout A: reg = a[11:7], qubits {0,1,2,3,4} masks {16,8,4,2,1}; t = a[6:0]
// Layout B: reg = a[7:3],  qubits {4,5,6,7,8} masks {16,8,4,2,1}; t = {a[11:8],a[2:0]}
// Layout C: reg = {a[3:0],a[11]}, qubits {8,9,10,11,0} masks {16,8,4,2,1}; t = a[10:4]

__device__ __forceinline__ int addrA(int r, int t) { return (r << 7) | t; }
__device__ __forceinline__ int addrB(int r, int t) { return ((t >> 3) << 8) | (r << 3) | (t & 7); }
__device__ __forceinline__ int addrC(int r, int t) { return ((r & 1) << 11) | (t << 4) | (r >> 1); }
// Per-transpose swizzles: both store and load phases at 4-lanes/bank-pair minimum
__device__ __forceinline__ int swzAB(int a) { return a ^ ((a >> 5) & 8); }
__device__ __forceinline__ int swzBC(int a) { return a ^ ((a >> 4) & 15) ^ ((a >> 5) & 8); }

// ---- packed fp32 complex primitives (VOP3P) — proven R8 ----
__device__ __forceinline__ F2 pk_mul_bl(F2 a, F2 u) {   // (a.x*u.x, a.y*u.x)
    F2 d;
    asm("v_pk_mul_f32 %0, %1, %2 op_sel:[0,0] op_sel_hi:[1,0]"
        : "=v"(d) : "v"(a), "v"(u));
    return d;
}
__device__ __forceinline__ void pk_cross(F2& d, F2 a, F2 u) {  // d += (-a.y*u.y, a.x*u.y)
    asm("v_pk_fma_f32 %0, %1, %2, %0 op_sel:[1,1,0] op_sel_hi:[0,1,1] neg_lo:[1,0,0]"
        : "+v"(d) : "v"(a), "v"(u));
}
__device__ __forceinline__ void pk_fma_bl(F2& d, F2 a, F2 u) { // d += (a.x*u.x, a.y*u.x)
    asm("v_pk_fma_f32 %0, %1, %2, %0 op_sel:[0,0,0] op_sel_hi:[1,0,1]"
        : "+v"(d) : "v"(a), "v"(u));
}
__device__ __forceinline__ void pk_swapneg(F2& d, F2 a, F2 cs) { // d += (a.y*cs.y, -a.x*cs.y)
    asm("v_pk_fma_f32 %0, %1, %2, %0 op_sel:[1,1,0] op_sel_hi:[0,1,1] neg_hi:[1,0,0]"
        : "+v"(d) : "v"(a), "v"(cs));
}
__device__ __forceinline__ void pk_fma(F2& d, F2 a, F2 b) {    // d += a*b
    asm("v_pk_fma_f32 %0, %1, %2, %0" : "+v"(d) : "v"(a), "v"(b));
}
__device__ __forceinline__ void pk_imacc(F2& d, F2 a0, F2 a1) { // d += (a0.x*a1.y, -a0.y*a1.x)
    asm("v_pk_fma_f32 %0, %1, %2, %0 op_sel:[0,1,0] op_sel_hi:[1,0,1] neg_hi:[1,0,0]"
        : "+v"(d) : "v"(a0), "v"(a1));
}
__device__ __forceinline__ F2 pk_cmul(F2 u, F2 a) {
    F2 d = pk_mul_bl(a, u);
    pk_cross(d, a, u);
    return d;
}
__device__ __forceinline__ void pk_cfma(F2& d, F2 u, F2 a) {
    pk_fma_bl(d, a, u);
    pk_cross(d, a, u);
}

__device__ __forceinline__ void build_u(float tx, float ty, float tz, float* u) {
    float sx = sinf(0.5f*tx), cx = cosf(0.5f*tx);
    float sy = sinf(0.5f*ty), cy = cosf(0.5f*ty);
    float sz = sinf(0.5f*tz), cz = cosf(0.5f*tz);
    float A00r = cy*cx, A00i =  sy*sx;     // A = Ry*Rx
    float A01r = -sy*cx, A01i = -cy*sx;
    float A10r =  sy*cx, A10i = -cy*sx;
    float A11r =  cy*cx, A11i = -sy*sx;
    // U = Rz*A: row0 *= (cz - i sz), row1 *= (cz + i sz)   [verified r1/3/5/6/7/8]
    u[0] = cz*A00r + sz*A00i;  u[1] = cz*A00i - sz*A00r;
    u[2] = cz*A01r + sz*A01i;  u[3] = cz*A01i - sz*A01r;
    u[4] = cz*A10r - sz*A10i;  u[5] = cz*A10i + sz*A10r;
    u[6] = cz*A11r - sz*A11i;  u[7] = cz*A11i + sz*A11r;
}

// coef layout (floats): [0..95] U0 plain (q*8); [96..191] RX(ang[36+q-1])*U0[q] (q=1..11);
// [192..287] U1 plain; [288..295] U1[0]*RX(ang[47]); [296..319] L1 CRX (cos,sin)[c=0..11]
__global__ void prep_kernel(const float* __restrict__ ang, float* __restrict__ coef) {
    int t = threadIdx.x;
    if (t < 12) {
        float u[8]; build_u(ang[t], ang[12+t], ang[24+t], u);
#pragma unroll
        for (int j = 0; j < 8; ++j) coef[t*8 + j] = u[j];
    } else if (t < 24) {
        int q = t - 12;
        float u[8]; build_u(ang[48+q], ang[60+q], ang[72+q], u);
#pragma unroll
        for (int j = 0; j < 8; ++j) coef[192 + q*8 + j] = u[j];
    } else if (t < 36) {
        int c = t - 24;
        float th = 0.5f * ang[95 - c];     // L1 ring gate (c,c+1) = tape slot 84+(11-c)
        coef[296 + c*2]     = cosf(th);
        coef[296 + c*2 + 1] = sinf(th);
    } else if (t < 47) {
        int q = t - 35;                    // 1..11: M = RX(ang[36+q-1]) * U0[q]
        float u[8]; build_u(ang[q], ang[12+q], ang[24+q], u);
        float c = cosf(0.5f*ang[36+q-1]), s = sinf(0.5f*ang[36+q-1]);
        float m[8];
        m[0] = c*u[0] + s*u[5];  m[1] = c*u[1] - s*u[4];   // M00 = c u00 - i s u10
        m[2] = c*u[2] + s*u[7];  m[3] = c*u[3] - s*u[6];   // M01 = c u01 - i s u11
        m[4] = s*u[1] + c*u[4];  m[5] = -s*u[0] + c*u[5];  // M10 = -i s u00 + c u10
        m[6] = s*u[3] + c*u[6];  m[7] = -s*u[2] + c*u[7];  // M11 = -i s u01 + c u11
#pragma unroll
        for (int j = 0; j < 8; ++j) coef[96 + q*8 + j] = m[j];
    } else if (t == 47) {                  // M = U1[0] * RX(ang[47])  [CR0(11,0) then U1(0)]
        float u[8]; build_u(ang[48], ang[60], ang[72], u);
        float c = cosf(0.5f*ang[47]), s = sinf(0.5f*ang[47]);
        float m[8];
        m[0] = c*u[0] + s*u[3];  m[1] = c*u[1] - s*u[2];   // M00 = c u00 - i s u01
        m[2] = s*u[1] + c*u[2];  m[3] = -s*u[0] + c*u[3];  // M01 = -i s u00 + c u01
        m[4] = c*u[4] + s*u[7];  m[5] = c*u[5] - s*u[6];   // M10 = c u10 - i s u11
        m[6] = s*u[5] + c*u[6];  m[7] = -s*u[4] + c*u[7];  // M11 = -i s u10 + c u11
#pragma unroll
        for (int j = 0; j < 8; ++j) coef[288 + j] = m[j];
    }
}

template<int M>  // plain fused-1q on reg-bit M pairs (16 pairs over 32 regs)
__device__ __forceinline__ void g1q(F2* amp, const float* __restrict__ u) {
    F2 u00 = {u[0], u[1]}, u01 = {u[2], u[3]};
    F2 u10 = {u[4], u[5]}, u11 = {u[6], u[7]};
#pragma unroll
    for (int r0 = 0; r0 < 32; ++r0) {
        if (r0 & M) continue;
        const int r1 = r0 + M;
        F2 a0 = amp[r0], a1 = amp[r1];
        F2 n0 = pk_cmul(u00, a0); pk_cfma(n0, u01, a1);
        F2 n1 = pk_cmul(u10, a0); pk_cfma(n1, u11, a1);
        amp[r0] = n0; amp[r1] = n1;
    }
}

// 1q gate with matrix selected by compile-time control reg bit MSEL:
// sel=0 -> uA (plain), sel=1 -> uB (CRX-fused product). Zero runtime select cost.
template<int MSEL, int M>
__device__ __forceinline__ void fg1q(F2* amp, const float* __restrict__ uA,
                                     const float* __restrict__ uB) {
    F2 a00 = {uA[0], uA[1]}, a01 = {uA[2], uA[3]}, a10 = {uA[4], uA[5]}, a11 = {uA[6], uA[7]};
    F2 b00 = {uB[0], uB[1]}, b01 = {uB[2], uB[3]}, b10 = {uB[4], uB[5]}, b11 = {uB[6], uB[7]};
#pragma unroll
    for (int r0 = 0; r0 < 32; ++r0) {
        if (r0 & M) continue;
        const int r1 = r0 + M;
        const bool sel = (r0 & MSEL) != 0;           // compile-time
        F2 u00 = sel ? b00 : a00, u01 = sel ? b01 : a01;
        F2 u10 = sel ? b10 : a10, u11 = sel ? b11 : a11;
        F2 a0 = amp[r0], a1 = amp[r1];
        F2 n0 = pk_cmul(u00, a0); pk_cfma(n0, u01, a1);
        F2 n1 = pk_cmul(u10, a0); pk_cfma(n1, u11, a1);
        amp[r0] = n0; amp[r1] = n1;
    }
}

template<int MC, int MT>  // plain CRX (8 pairs over 32 regs)
__device__ __forceinline__ void crx(F2* amp, F2 cs) {
#pragma unroll
    for (int r0 = 0; r0 < 32; ++r0) {
        if (!(r0 & MC) || (r0 & MT)) continue;
        const int r1 = r0 + MT;
        F2 a0 = amp[r0], a1 = amp[r1];
        F2 n0 = pk_mul_bl(a0, cs); pk_swapneg(n0, a1, cs);
        F2 n1 = pk_mul_bl(a1, cs); pk_swapneg(n1, a0, cs);
        amp[r0] = n0; amp[r1] = n1;
    }
}

template<int M>  // wave-reduce <X_q>,<Y_q>,<Z_q>; park totals in lane q
__device__ __forceinline__ void expv(const F2* amp, int q, int lane,
                                     float& fx, float& fy, float& fz) {
    F2 zp = {0.f, 0.f}, zm = {0.f, 0.f}, xp = {0.f, 0.f}, ip = {0.f, 0.f};
#pragma unroll
    for (int r0 = 0; r0 < 32; ++r0) {
        if (r0 & M) continue;
        const int r1 = r0 + M;
        F2 a0 = amp[r0], a1 = amp[r1];
        pk_fma(zp, a0, a0);
        pk_fma(zm, a1, a1);
        pk_fma(xp, a0, a1);
        pk_imacc(ip, a0, a1);
    }
    float zz = (zp.x + zp.y) - (zm.x + zm.y);
    float xr = 2.f * (xp.x + xp.y);
    float xi = 2.f * (ip.x + ip.y);
#pragma unroll
    for (int off = 32; off; off >>= 1) {
        xr += __shfl_xor(xr, off);
        xi += __shfl_xor(xi, off);
        zz += __shfl_xor(zz, off);
    }
    if (lane == q) { fx = xr; fy = xi; fz = zz; }
}

#define XPOSE(CUR, NXT, SWZ) \
  { _Pragma("unroll") for (int r = 0; r < 32; ++r) psi[SWZ(CUR(r, t))] = amp[r]; \
    __syncthreads(); \
    _Pragma("unroll") for (int r = 0; r < 32; ++r) amp[r] = psi[SWZ(NXT(r, t))]; \
    __syncthreads(); }

#define U0P(q, M)        g1q<M>(amp, cf + (q)*8)
#define FU0(q, MSEL, M)  fg1q<MSEL, M>(amp, cf + (q)*8, cf + 96 + (q)*8)
#define U1P(q, M)        g1q<M>(amp, cf + 192 + (q)*8)
#define FU1_0()          fg1q<2, 1>(amp, cf + 192, cf + 288)
#define CR1(c, MC, MT)   crx<MC, MT>(amp, F2{cf[296 + (c)*2], cf[296 + (c)*2 + 1]})
#define EXPV(q, M)       expv<M>(amp, q, lane, fx, fy, fz)

__global__ __launch_bounds__(128, 1)
void qsim_kernel(const float* __restrict__ sv,      // [B, 4096]
                 const float* __restrict__ cf,      // [320] precomputed coefficients
                 const float* __restrict__ W,       // [10, 36]
                 const float* __restrict__ bvec,    // [10]
                 float* __restrict__ out)           // [B, 10]
{
    __shared__ F2 psi[DIM];          // exactly 32 KB
    const int t = threadIdx.x;
    const int b = blockIdx.x;
    const int lane = t & 63, w = t >> 6;

    F2 amp[32];
    const float* svb = sv + (size_t)b * DIM;
#pragma unroll
    for (int r = 0; r < 32; ++r)                    // layout A, coalesced
        amp[r] = make_float2(svb[(r << 7) | t], 0.f);

    float fx = 0.f, fy = 0.f, fz = 0.f;

    // ---- A {0,1,2,3,4}: U0(0); [U0(q);CR0(q-1,q)] for q=1..4 ----
    U0P(0, 16);
    FU0(1, 16, 8); FU0(2, 8, 4); FU0(3, 4, 2); FU0(4, 2, 1);
    XPOSE(addrA, addrB, swzAB);

    // ---- B {4,5,6,7,8}: [U0(q);CR0(q-1,q)] for q=5..8 ----
    FU0(5, 16, 8); FU0(6, 8, 4); FU0(7, 4, 2); FU0(8, 2, 1);
    XPOSE(addrB, addrC, swzBC);

    // ---- C {8,9,10,11,0}: [U0(q);CR0(q-1,q)] q=9..11; [CR0(11,0);U1(0)];
    //      U1(8..11); L1 ring (11,0),(10,11),(9,10),(8,9); expv 9,10,11 ----
    FU0(9, 16, 8); FU0(10, 8, 4); FU0(11, 4, 2);
    FU1_0();
    U1P(8, 16); U1P(9, 8); U1P(10, 4); U1P(11, 2);
    CR1(11, 2, 1); CR1(10, 4, 2); CR1(9, 8, 4); CR1(8, 16, 8);
    EXPV(9, 8); EXPV(10, 4); EXPV(11, 2);
    XPOSE(addrC, addrB, swzBC);

    // ---- B' {4,5,6,7,8}: U1(4..7); L1 ring (7,8),(6,7),(5,6),(4,5); expv 5,6,7,8 ----
    U1P(4, 16); U1P(5, 8); U1P(6, 4); U1P(7, 2);
    CR1(7, 2, 1); CR1(6, 4, 2); CR1(5, 8, 4); CR1(4, 16, 8);
    EXPV(5, 8); EXPV(6, 4); EXPV(7, 2); EXPV(8, 1);
    XPOSE(addrB, addrA, swzAB);

    // ---- A' {0,1,2,3,4}: U1(1,2,3); L1 ring (3,4),(2,3),(1,2),(0,1); expv 0..4 ----
    U1P(1, 8); U1P(2, 4); U1P(3, 2);
    CR1(3, 2, 1); CR1(2, 4, 2); CR1(1, 8, 4); CR1(0, 16, 8);
    EXPV(0, 16); EXPV(1, 8); EXPV(2, 4); EXPV(3, 2); EXPV(4, 1);

    // ---- combine 2 waves' features (psi dead: alias), head, store ----
    float* fbuf = (float*)psi;       // [2][36]
    if (lane < 12) {
        fbuf[w * 36 + lane]      = fx;
        fbuf[w * 36 + 12 + lane] = fy;
        fbuf[w * 36 + 24 + lane] = fz;
    }
    __syncthreads();
    if (t < 10) {
        float a = bvec[t];
#pragma unroll
        for (int f = 0; f < 36; ++f)
            a += W[t * 36 + f] * (fbuf[f] + fbuf[36 + f]);
        out[(size_t)b * 10 + t] = a;
    }
}

extern "C" void kernel_launch(void* const* d_in, const int* in_sizes, int n_in,
                              void* d_out, int out_size, void* d_ws, size_t ws_size,
                              hipStream_t stream) {
    const float* sv     = (const float*)d_in[0];
    const float* angles = (const float*)d_in[1];
    const float* W      = (const float*)d_in[2];
    const float* bvec   = (const float*)d_in[3];
    float* out  = (float*)d_out;
    float* coef = (float*)d_ws;      // 320 floats of scratch
    int batch = in_sizes[0] / DIM;   // 2048
    prep_kernel<<<1, 64, 0, stream>>>(angles, coef);
    qsim_kernel<<<batch, 128, 0, stream>>>(sv, coef, W, bvec, out);
}